// Round 3
// baseline (841.697 us; speedup 1.0000x reference)
//
#include <hip/hip_runtime.h>
#include <hip/hip_bf16.h>

#define BATCH   16
#define NPTS    2048
#define NPOINT  512
#define CFEAT   128
#define CIN     131
#define CMID    32

typedef _Float16 half8 __attribute__((ext_vector_type(8)));
typedef float floatx4 __attribute__((ext_vector_type(4)));

// exact (non-contracted) squared distance, matching jnp's ((dx^2+dy^2)+dz^2)
__device__ __forceinline__ float d2_rn(float ax, float ay, float az,
                                       float bx, float by, float bz) {
  float dx = __fsub_rn(ax, bx), dy = __fsub_rn(ay, by), dz = __fsub_rn(az, bz);
  return __fadd_rn(__fadd_rn(__fmul_rn(dx, dx), __fmul_rn(dy, dy)), __fmul_rn(dz, dz));
}

// 64-lane lexicographic max of (hi,lo) key, result in lane 63.
__device__ __forceinline__ void wave_key_reduce(unsigned &hi, unsigned &lo) {
#define KSTEP(CTRL, RM, BM) {                                                     \
    unsigned h2 = (unsigned)__builtin_amdgcn_update_dpp((int)hi, (int)hi, CTRL,   \
                                                        RM, BM, false);           \
    unsigned l2 = (unsigned)__builtin_amdgcn_update_dpp((int)lo, (int)lo, CTRL,   \
                                                        RM, BM, false);           \
    bool g = (h2 > hi) || (h2 == hi && l2 > lo);                                  \
    hi = g ? h2 : hi; lo = g ? l2 : lo; }
  KSTEP(0x111, 0xf, 0xf)   // row_shr:1
  KSTEP(0x112, 0xf, 0xf)   // row_shr:2
  KSTEP(0x114, 0xf, 0xe)   // row_shr:4
  KSTEP(0x118, 0xf, 0xc)   // row_shr:8
  KSTEP(0x142, 0xa, 0xf)   // row_bcast:15
  KSTEP(0x143, 0xc, 0xf)   // row_bcast:31
#undef KSTEP
}

// blocks [0,16): FPS per batch; blocks [16, 16+4096): transpose features -> featT
__global__ __launch_bounds__(256) void fps_transpose_kernel(
    const float* __restrict__ xyz, const float* __restrict__ feat,
    float* __restrict__ featT, float* __restrict__ out_xyz)
{
  int t = threadIdx.x;
  if (blockIdx.x >= BATCH) {
    __shared__ float tile[32][33];
    int m  = blockIdx.x - BATCH;
    int b  = m >> 8;
    int c0 = ((m >> 6) & 3) << 5;
    int n0 = (m & 63) << 5;
    int tx = t & 31, ty = t >> 5;
    const float* src = feat  + (size_t)b * CFEAT * NPTS;
    float*       dst = featT + (size_t)b * NPTS * CFEAT;
#pragma unroll
    for (int i = 0; i < 4; ++i)
      tile[ty + 8 * i][tx] = src[(size_t)(c0 + ty + 8 * i) * NPTS + n0 + tx];
    __syncthreads();
#pragma unroll
    for (int i = 0; i < 4; ++i)
      dst[(size_t)(n0 + ty + 8 * i) * CFEAT + c0 + tx] = tile[tx][ty + 8 * i];
    return;
  }
  // ---- FPS: one block per batch, 256 threads, 8 pts/thread, all in registers ----
  __shared__ uint4 slotA[2][4];   // {key_lo, key_hi, x_bits, y_bits} per wave
  __shared__ float slotB[2][4];   // z per wave
  int b = blockIdx.x, lane = t & 63, wid = t >> 6;
  const float* xb = xyz + (size_t)b * NPTS * 3;
  float px[8], py[8], pz[8], d[8]; unsigned nlo[8];
#pragma unroll
  for (int i = 0; i < 8; ++i) {
    int n = (i << 8) + t;
    px[i] = xb[n * 3 + 0]; py[i] = xb[n * 3 + 1]; pz[i] = xb[n * 3 + 2];
    d[i] = 1e10f;
    nlo[i] = ~(unsigned)n;      // bigger ~n == smaller n -> argmax first-occurrence
  }
  float cx = xb[0], cy = xb[1], cz = xb[2];
  if (t == 0) {
    float* o = out_xyz + (size_t)b * NPOINT * 3;
    o[0] = cx; o[1] = cy; o[2] = cz;
  }
#pragma unroll 1
  for (int step = 1; step < NPOINT; ++step) {
    unsigned bhi = 0u, blo = 0u;
#pragma unroll
    for (int i = 0; i < 8; ++i) {
      float dd = d2_rn(px[i], py[i], pz[i], cx, cy, cz);
      float nd = fminf(d[i], dd);
      d[i] = nd;
      unsigned hb = __float_as_uint(nd);
      bool g = (hb > bhi) || (hb == bhi && nlo[i] > blo);
      bhi = g ? hb : bhi; blo = g ? nlo[i] : blo;
    }
    wave_key_reduce(bhi, blo);
    unsigned whi = (unsigned)__builtin_amdgcn_readlane((int)bhi, 63);
    unsigned wlo = (unsigned)__builtin_amdgcn_readlane((int)blo, 63);
    unsigned nw = ~wlo;
    int iw = (int)((nw >> 8) & 7);
    int src = (int)(nw & 63);
    // wave winner's coords (owner wave reads real values; others' slots lose)
    float sxv = px[0], syv = py[0], szv = pz[0];
#pragma unroll
    for (int i = 1; i < 8; ++i)
      if (iw == i) { sxv = px[i]; syv = py[i]; szv = pz[i]; }
    float xw = __uint_as_float((unsigned)__builtin_amdgcn_readlane(__float_as_int(sxv), src));
    float yw = __uint_as_float((unsigned)__builtin_amdgcn_readlane(__float_as_int(syv), src));
    float zw = __uint_as_float((unsigned)__builtin_amdgcn_readlane(__float_as_int(szv), src));
    int p = step & 1;
    if (lane == 0) {
      slotA[p][wid] = make_uint4(wlo, whi, __float_as_uint(xw), __float_as_uint(yw));
      slotB[p][wid] = zw;
    }
    __syncthreads();
    uint4 a0 = slotA[p][0], a1 = slotA[p][1], a2 = slotA[p][2], a3 = slotA[p][3];
    float z0 = slotB[p][0], z1 = slotB[p][1], z2 = slotB[p][2], z3 = slotB[p][3];
    bool g1 = (a1.y > a0.y) || (a1.y == a0.y && a1.x > a0.x);
    uint4 ka = g1 ? a1 : a0; float za = g1 ? z1 : z0;
    bool g2 = (a3.y > a2.y) || (a3.y == a2.y && a3.x > a2.x);
    uint4 kb = g2 ? a3 : a2; float zb = g2 ? z3 : z2;
    bool g3 = (kb.y > ka.y) || (kb.y == ka.y && kb.x > ka.x);
    uint4 kf = g3 ? kb : ka; float zf = g3 ? zb : za;
    cx = __uint_as_float(kf.z); cy = __uint_as_float(kf.w); cz = zf;
    if (t == 0) {
      float* o = out_xyz + ((size_t)b * NPOINT + step) * 3;
      o[0] = cx; o[1] = cy; o[2] = cz;
    }
  }
}

// one block per (center j, batch b), 256 threads.
__global__ __launch_bounds__(256) void center_kernel(
    const float* __restrict__ xyz, const float* __restrict__ featT,
    const float* __restrict__ W1, const float* __restrict__ b1,
    const float* __restrict__ W2, const float* __restrict__ b2,
    const float* __restrict__ Wcr, const float* __restrict__ bcr,
    const float* __restrict__ new_xyz, float* __restrict__ out_feat)
{
  int j = blockIdx.x, b = blockIdx.y, t = threadIdx.x;
  int wid = t >> 6, lane = t & 63;
  __shared__ _Float16 sW2T[144][32];    // A operand: [channel m][k]
  __shared__ _Float16 sH1T[96][32];     // B operand: [sample n][k]
  __shared__ float sB2[144];
  __shared__ float sRel[96][4];
  __shared__ int   sIdx[96];
  __shared__ int   lI0[4][16], lI1[4][32], lI2[4][48];
  __shared__ int   lC[4][3];
  __shared__ int   pooledI[3][144];     // relu(...) >= 0 -> int-bit max == float max

  // ---- Phase A: stage weights, init pooled; each wave ball-queries a 512-pt range
  for (int i = t; i < 144 * 32; i += 256) {
    int m = i >> 5, k = i & 31;
    float v = (m < CIN) ? W2[k * CIN + m] : 0.f;
    sW2T[m][k] = (_Float16)v;
  }
  if (t < 144) sB2[t] = (t < CIN) ? b2[t] : 0.f;
  for (int i = t; i < 3 * 144; i += 256) ((int*)pooledI)[i] = 0;

  float cx = new_xyz[((size_t)b * NPOINT + j) * 3 + 0];
  float cy = new_xyz[((size_t)b * NPOINT + j) * 3 + 1];
  float cz = new_xyz[((size_t)b * NPOINT + j) * 3 + 2];

  {
    const float* xb = xyz + (size_t)b * NPTS * 3;
    unsigned long long lt = (1ull << lane) - 1ull;
    int c0 = 0, c1 = 0, c2 = 0;
    for (int it = 0; it < 8; ++it) {
      int n = (wid << 9) + (it << 6) + lane;
      float px = xb[n * 3 + 0], py = xb[n * 3 + 1], pz = xb[n * 3 + 2];
      float d2 = d2_rn(cx, cy, cz, px, py, pz);
      bool i0 = d2 < 0.01f, i1 = d2 < 0.04f, i2 = d2 < 0.16f;
      unsigned long long m0 = __ballot(i0), m1 = __ballot(i1), m2 = __ballot(i2);
      if (i0) { int p = c0 + __popcll(m0 & lt); if (p < 16) lI0[wid][p] = n; }
      if (i1) { int p = c1 + __popcll(m1 & lt); if (p < 32) lI1[wid][p] = n; }
      if (i2) { int p = c2 + __popcll(m2 & lt); if (p < 48) lI2[wid][p] = n; }
      c0 += __popcll(m0); c1 += __popcll(m1); c2 += __popcll(m2);
    }
    if (lane == 0) { lC[wid][0] = c0; lC[wid][1] = c1; lC[wid][2] = c2; }
  }
  __syncthreads();

  // ---- Phase B: merge ranges (exact first-k ascending) + h1 for own sample
  if (t < 96) {
    int rad = (t < 16) ? 0 : ((t < 48) ? 1 : 2);
    int g = t - ((rad == 0) ? 0 : ((rad == 1) ? 16 : 48));
    int q0 = lC[0][rad], q1 = lC[1][rad], q2 = lC[2][rad], q3 = lC[3][rad];
    const int* L0 = (rad == 0) ? lI0[0] : (rad == 1) ? lI1[0] : lI2[0];
    const int* L1 = (rad == 0) ? lI0[1] : (rad == 1) ? lI1[1] : lI2[1];
    const int* L2 = (rad == 0) ? lI0[2] : (rad == 1) ? lI1[2] : lI2[2];
    const int* L3 = (rad == 0) ? lI0[3] : (rad == 1) ? lI1[3] : lI2[3];
    int idx = -1, gg = g;
    if (gg < q0) idx = L0[gg]; else { gg -= q0;
    if (gg < q1) idx = L1[gg]; else { gg -= q1;
    if (gg < q2) idx = L2[gg]; else { gg -= q2;
    if (gg < q3) idx = L3[gg]; } } }
    if (idx < 0)   // pad with first in-ball index overall (guaranteed nonempty)
      idx = (q0 > 0) ? L0[0] : (q1 > 0) ? L1[0] : (q2 > 0) ? L2[0] : L3[0];
    sIdx[t] = idx;

    const float* pp = xyz + ((size_t)b * NPTS + (size_t)idx) * 3;
    float ppx = pp[0], ppy = pp[1], ppz = pp[2];
    float rx = __fsub_rn(ppx, cx), ry = __fsub_rn(ppy, cy), rz = __fsub_rn(ppz, cz);
    float dist = sqrtf(__fadd_rn(__fadd_rn(__fmul_rn(rx, rx), __fmul_rn(ry, ry)),
                                 __fmul_rn(rz, rz)));
    sRel[t][0] = rx; sRel[t][1] = ry; sRel[t][2] = rz; sRel[t][3] = 0.f;
    float h10[10] = {dist, cx, cy, cz, ppx, ppy, ppz, rx, ry, rz};
    _Float16 h1h[CMID];
#pragma unroll
    for (int k = 0; k < CMID; ++k) {
      float a = b1[k];
#pragma unroll
      for (int i = 0; i < 10; ++i) a = fmaf(h10[i], W1[i * CMID + k], a);
      h1h[k] = (_Float16)fmaxf(a, 0.f);
    }
    uint4* dstv = (uint4*)&sH1T[t][0];
    const uint4* srcv = (const uint4*)h1h;
#pragma unroll
    for (int q = 0; q < 4; ++q) dstv[q] = srcv[q];
  }
  __syncthreads();

  // ---- Phase C: h2 via MFMA; relu(h2*x); segmented max-pool ----
  const float* ftb = featT + (size_t)b * NPTS * CFEAT;
  int quad = lane >> 4, col = lane & 15;
#pragma unroll 1
  for (int tile = wid; tile < 54; tile += 4) {
    int mt = tile % 9, nt = tile / 9;
    int m0 = mt << 4, n0 = nt << 4;
    half8 A = *(const half8*)&sW2T[m0 + col][quad << 3];
    int sample = n0 + col;
    half8 Bv = *(const half8*)&sH1T[sample][quad << 3];
    floatx4 acc = {0.f, 0.f, 0.f, 0.f};
    acc = __builtin_amdgcn_mfma_f32_16x16x32_f16(A, Bv, acc, 0, 0, 0);
    int sidx = sIdx[sample];
    int cb = m0 + (quad << 2);
    int seg = (nt == 0) ? 0 : ((nt < 3) ? 1 : 2);
    float v[4];
#pragma unroll
    for (int r = 0; r < 4; ++r) {
      int c = cb + r;
      float h2 = __fadd_rn(acc[r], sB2[c]);
      float x;
      if (c < 3) x = sRel[sample][c];
      else {
        int off = c - 3; if (off > 127) off = 0;
        x = ftb[(size_t)sidx * CFEAT + off];
        if (c >= CIN) x = 0.f;
      }
      v[r] = fmaxf(__fmul_rn(h2, x), 0.f);
    }
#pragma unroll
    for (int msk = 1; msk < 16; msk <<= 1) {
#pragma unroll
      for (int r = 0; r < 4; ++r) v[r] = fmaxf(v[r], __shfl_xor(v[r], msk));
    }
    if (col == 0) {
#pragma unroll
      for (int r = 0; r < 4; ++r)
        atomicMax(&pooledI[seg][cb + r], __float_as_int(v[r]));
    }
  }
  __syncthreads();

  // ---- Phase D: out = relu(pooled @ Wcr + bcr) ----
  if (t < CFEAT) {
    float s0 = bcr[t], s1 = s0, s2 = s0;
#pragma unroll 4
    for (int k = 0; k < CIN; ++k) {
      float w = Wcr[k * CFEAT + t];
      s0 = fmaf(__int_as_float(pooledI[0][k]), w, s0);
      s1 = fmaf(__int_as_float(pooledI[1][k]), w, s1);
      s2 = fmaf(__int_as_float(pooledI[2][k]), w, s2);
    }
    float* ob = out_feat + (size_t)b * 384 * NPOINT + j;
    ob[(size_t)(0 * CFEAT + t) * NPOINT] = fmaxf(s0, 0.f);
    ob[(size_t)(1 * CFEAT + t) * NPOINT] = fmaxf(s1, 0.f);
    ob[(size_t)(2 * CFEAT + t) * NPOINT] = fmaxf(s2, 0.f);
  }
}

extern "C" void kernel_launch(void* const* d_in, const int* in_sizes, int n_in,
                              void* d_out, int out_size, void* d_ws, size_t ws_size,
                              hipStream_t stream) {
  const float* xyz  = (const float*)d_in[0];
  const float* feat = (const float*)d_in[1];
  const float* W1   = (const float*)d_in[2];
  const float* b1   = (const float*)d_in[3];
  const float* W2   = (const float*)d_in[4];
  const float* b2   = (const float*)d_in[5];
  const float* Wcr  = (const float*)d_in[6];
  const float* bcr  = (const float*)d_in[7];
  float* out_xyz  = (float*)d_out;                          // (B, 512, 3)
  float* out_feat = out_xyz + (size_t)BATCH * NPOINT * 3;   // (B, 384, 512)
  float* featT    = (float*)d_ws;                           // (B, N, C) 16 MB

  fps_transpose_kernel<<<BATCH + BATCH * 256, 256, 0, stream>>>(xyz, feat, featT, out_xyz);
  center_kernel<<<dim3(NPOINT, BATCH), 256, 0, stream>>>(
      xyz, featT, W1, b1, W2, b2, Wcr, bcr, (const float*)d_out, out_feat);
}

// Round 4
// 580.607 us; speedup vs baseline: 1.4497x; 1.4497x over previous
//
#include <hip/hip_runtime.h>
#include <hip/hip_bf16.h>

#define BATCH   16
#define NPTS    2048
#define NPOINT  512
#define CFEAT   128
#define CIN     131
#define CMID    32

typedef _Float16 half8 __attribute__((ext_vector_type(8)));
typedef float floatx4 __attribute__((ext_vector_type(4)));

// exact (non-contracted) squared distance, matching jnp's ((dx^2+dy^2)+dz^2)
__device__ __forceinline__ float d2_rn(float ax, float ay, float az,
                                       float bx, float by, float bz) {
  float dx = __fsub_rn(ax, bx), dy = __fsub_rn(ay, by), dz = __fsub_rn(az, bz);
  return __fadd_rn(__fadd_rn(__fmul_rn(dx, dx), __fmul_rn(dy, dy)), __fmul_rn(dz, dz));
}

// 64-lane lexicographic max of (hi,lo), result lands in lane 63.
__device__ __forceinline__ void wave_key_reduce(unsigned &hi, unsigned &lo) {
#define KSTEP(CTRL, RM, BM) {                                                     \
    unsigned h2 = (unsigned)__builtin_amdgcn_update_dpp((int)hi, (int)hi, CTRL,   \
                                                        RM, BM, false);           \
    unsigned l2 = (unsigned)__builtin_amdgcn_update_dpp((int)lo, (int)lo, CTRL,   \
                                                        RM, BM, false);           \
    bool g = (h2 > hi) || (h2 == hi && l2 > lo);                                  \
    hi = g ? h2 : hi; lo = g ? l2 : lo; }
  KSTEP(0x111, 0xf, 0xf)   // row_shr:1
  KSTEP(0x112, 0xf, 0xf)   // row_shr:2
  KSTEP(0x114, 0xf, 0xe)   // row_shr:4
  KSTEP(0x118, 0xf, 0xc)   // row_shr:8
  KSTEP(0x142, 0xa, 0xf)   // row_bcast:15
  KSTEP(0x143, 0xc, 0xf)   // row_bcast:31
#undef KSTEP
}

// blocks [0,16): FPS per batch; blocks [16, 16+4096): transpose features -> featT
// (256,1): 1 wave/EU min -> full VGPR budget, no spill of the coord arrays.
__global__ __launch_bounds__(256, 1) void fps_transpose_kernel(
    const float* __restrict__ xyz, const float* __restrict__ feat,
    float* __restrict__ featT, float* __restrict__ out_xyz)
{
  int t = threadIdx.x;
  if (blockIdx.x >= BATCH) {
    __shared__ float tile[32][33];
    int m  = blockIdx.x - BATCH;
    int b  = m >> 8;
    int c0 = ((m >> 6) & 3) << 5;
    int n0 = (m & 63) << 5;
    int tx = t & 31, ty = t >> 5;
    const float* src = feat  + (size_t)b * CFEAT * NPTS;
    float*       dst = featT + (size_t)b * NPTS * CFEAT;
#pragma unroll
    for (int i = 0; i < 4; ++i)
      tile[ty + 8 * i][tx] = src[(size_t)(c0 + ty + 8 * i) * NPTS + n0 + tx];
    __syncthreads();
#pragma unroll
    for (int i = 0; i < 4; ++i)
      dst[(size_t)(n0 + ty + 8 * i) * CFEAT + c0 + tx] = tile[tx][ty + 8 * i];
    return;
  }
  // ---- FPS: one block per batch, 256 threads, 8 pts/thread in registers ----
  __shared__ float4 sp[NPTS];                 // 32 KB (also winner-coord source)
  __shared__ unsigned long long skey[2][4];
  int b = blockIdx.x, lane = t & 63, wid = t >> 6;
  const float* xb = xyz + (size_t)b * NPTS * 3;
  for (int n = t; n < NPTS; n += 256) {
    const float* p = xb + n * 3;
    sp[n] = make_float4(p[0], p[1], p[2], 0.f);
  }
  __syncthreads();
  float px[8], py[8], pz[8], d[8];
#pragma unroll
  for (int i = 0; i < 8; ++i) {
    float4 q = sp[(i << 8) + t];
    px[i] = q.x; py[i] = q.y; pz[i] = q.z;
    d[i] = 1e10f;
  }
  float cx, cy, cz;
  { float4 q = sp[0]; cx = q.x; cy = q.y; cz = q.z; }
  if (t == 0) {
    float* o = out_xyz + (size_t)b * NPOINT * 3;
    o[0] = cx; o[1] = cy; o[2] = cz;
  }
#pragma unroll 1
  for (int step = 1; step < NPOINT; ++step) {
    unsigned long long bk = 0ull;
#pragma unroll
    for (int i = 0; i < 8; ++i) {
      float dd = d2_rn(px[i], py[i], pz[i], cx, cy, cz);
      float nd = fminf(d[i], dd);
      d[i] = nd;
      // key = dist_bits : ~n  (bigger ~n == smaller n -> argmax first-occurrence)
      unsigned long long key = ((unsigned long long)__float_as_uint(nd) << 32)
                             | (unsigned)~((i << 8) + t);
      bk = key > bk ? key : bk;
    }
    unsigned khi = (unsigned)(bk >> 32), klo = (unsigned)bk;
    wave_key_reduce(khi, klo);
    int p = step & 1;   // double-buffered -> one barrier per step
    if (lane == 63)
      skey[p][wid] = ((unsigned long long)khi << 32) | (unsigned long long)klo;
    __syncthreads();
    unsigned long long k0 = skey[p][0], k1 = skey[p][1];
    unsigned long long k2 = skey[p][2], k3 = skey[p][3];
    unsigned long long ka = k0 > k1 ? k0 : k1;
    unsigned long long kb = k2 > k3 ? k2 : k3;
    unsigned long long km = ka > kb ? ka : kb;
    int last = (int)(~(unsigned)(km & 0xFFFFFFFFull)) & (NPTS - 1);
    float4 q = sp[last];            // broadcast read
    cx = q.x; cy = q.y; cz = q.z;
    if (t == 0) {
      float* o = out_xyz + ((size_t)b * NPOINT + step) * 3;
      o[0] = cx; o[1] = cy; o[2] = cz;
    }
  }
}

// one block per (center j, batch b), 256 threads.
// MFMA: A = H1 (samples on M), B = W2^T (channels on N).
__global__ __launch_bounds__(256) void center_kernel(
    const float* __restrict__ xyz, const float* __restrict__ featT,
    const float* __restrict__ W1, const float* __restrict__ b1,
    const float* __restrict__ W2, const float* __restrict__ b2,
    const float* __restrict__ Wcr, const float* __restrict__ bcr,
    const float* __restrict__ new_xyz, float* __restrict__ out_feat)
{
  int j = blockIdx.x, b = blockIdx.y, t = threadIdx.x;
  int wid = t >> 6, lane = t & 63;
  int quad = lane >> 4, col = lane & 15;
  // +8 half padding (40): bank stride 20 -> only 2-way conflict (free)
  __shared__ _Float16 sW2T[144][40];    // B operand: [channel n][k]
  __shared__ _Float16 sH1T[96][40];     // A operand: [sample m][k]
  __shared__ float sRel[96][4];
  __shared__ int   sIdx[96];
  __shared__ int   lI0[4][16], lI1[4][32], lI2[4][48];
  __shared__ int   lC[4][3];
  __shared__ float sPool[3][132];

  // ---- Phase A: stage W2^T (f16); each wave ball-queries a 512-pt range ----
  for (int i = t; i < 144 * 32; i += 256) {
    int m = i >> 5, k = i & 31;
    float v = (m < CIN) ? W2[k * CIN + m] : 0.f;
    sW2T[m][k] = (_Float16)v;
  }
  float cx = new_xyz[((size_t)b * NPOINT + j) * 3 + 0];
  float cy = new_xyz[((size_t)b * NPOINT + j) * 3 + 1];
  float cz = new_xyz[((size_t)b * NPOINT + j) * 3 + 2];
  {
    const float* xb = xyz + (size_t)b * NPTS * 3;
    unsigned long long lt = (1ull << lane) - 1ull;
    int c0 = 0, c1 = 0, c2 = 0;
    for (int it = 0; it < 8; ++it) {
      int n = (wid << 9) + (it << 6) + lane;
      float qx = xb[n * 3 + 0], qy = xb[n * 3 + 1], qz = xb[n * 3 + 2];
      float d2 = d2_rn(cx, cy, cz, qx, qy, qz);
      bool i0 = d2 < 0.01f, i1 = d2 < 0.04f, i2 = d2 < 0.16f;
      unsigned long long m0 = __ballot(i0), m1 = __ballot(i1), m2 = __ballot(i2);
      if (i0) { int p = c0 + __popcll(m0 & lt); if (p < 16) lI0[wid][p] = n; }
      if (i1) { int p = c1 + __popcll(m1 & lt); if (p < 32) lI1[wid][p] = n; }
      if (i2) { int p = c2 + __popcll(m2 & lt); if (p < 48) lI2[wid][p] = n; }
      c0 += __popcll(m0); c1 += __popcll(m1); c2 += __popcll(m2);
    }
    if (lane == 0) { lC[wid][0] = c0; lC[wid][1] = c1; lC[wid][2] = c2; }
  }
  __syncthreads();

  // ---- Phase B: merge ranges (exact first-k ascending) + h1 for own sample ----
  if (t < 96) {
    int rad = (t < 16) ? 0 : ((t < 48) ? 1 : 2);
    int g = t - ((rad == 0) ? 0 : ((rad == 1) ? 16 : 48));
    int q0 = lC[0][rad], q1 = lC[1][rad], q2 = lC[2][rad], q3 = lC[3][rad];
    const int* L0 = (rad == 0) ? lI0[0] : (rad == 1) ? lI1[0] : lI2[0];
    const int* L1 = (rad == 0) ? lI0[1] : (rad == 1) ? lI1[1] : lI2[1];
    const int* L2 = (rad == 0) ? lI0[2] : (rad == 1) ? lI1[2] : lI2[2];
    const int* L3 = (rad == 0) ? lI0[3] : (rad == 1) ? lI1[3] : lI2[3];
    int idx = -1, gg = g;
    if (gg < q0) idx = L0[gg]; else { gg -= q0;
    if (gg < q1) idx = L1[gg]; else { gg -= q1;
    if (gg < q2) idx = L2[gg]; else { gg -= q2;
    if (gg < q3) idx = L3[gg]; } } }
    if (idx < 0)   // pad with first in-ball index (center itself is in-ball)
      idx = (q0 > 0) ? L0[0] : (q1 > 0) ? L1[0] : (q2 > 0) ? L2[0] : L3[0];
    sIdx[t] = idx;

    const float* pp = xyz + ((size_t)b * NPTS + (size_t)idx) * 3;
    float ppx = pp[0], ppy = pp[1], ppz = pp[2];
    float rx = __fsub_rn(ppx, cx), ry = __fsub_rn(ppy, cy), rz = __fsub_rn(ppz, cz);
    float dist = sqrtf(__fadd_rn(__fadd_rn(__fmul_rn(rx, rx), __fmul_rn(ry, ry)),
                                 __fmul_rn(rz, rz)));
    sRel[t][0] = rx; sRel[t][1] = ry; sRel[t][2] = rz; sRel[t][3] = 0.f;
    float h10[10] = {dist, cx, cy, cz, ppx, ppy, ppz, rx, ry, rz};
    _Float16 h1h[CMID];
#pragma unroll
    for (int k = 0; k < CMID; ++k) {
      float a = b1[k];
#pragma unroll
      for (int i = 0; i < 10; ++i) a = fmaf(h10[i], W1[i * CMID + k], a);
      h1h[k] = (_Float16)fmaxf(a, 0.f);
    }
    uint4* dstv = (uint4*)&sH1T[t][0];
    const uint4* srcv = (const uint4*)h1h;
#pragma unroll
    for (int q = 0; q < 4; ++q) dstv[q] = srcv[q];
  }
  __syncthreads();

  // ---- Phase C: h2 via MFMA, relu(h2*x), segmented max-pool ----
  const float* ftb = featT + (size_t)b * NPTS * CFEAT;
#pragma unroll 1
  for (int nt = wid; nt < 9; nt += 4) {
    int c = (nt << 4) + col;
    half8 Bv = *(const half8*)&sW2T[c][quad << 3];   // fixed per n-tile
    float b2c = (c < CIN) ? b2[c] : 0.f;
    float sm0 = 0.f, sm1 = 0.f, sm2 = 0.f;
#pragma unroll
    for (int mt = 0; mt < 6; ++mt) {
      half8 A = *(const half8*)&sH1T[(mt << 4) + col][quad << 3];
      floatx4 acc = {0.f, 0.f, 0.f, 0.f};
      acc = __builtin_amdgcn_mfma_f32_16x16x32_f16(A, Bv, acc, 0, 0, 0);
#pragma unroll
      for (int r = 0; r < 4; ++r) {
        int sm = (mt << 4) + (quad << 2) + r;     // sample (D row)
        float x;
        if (c < 3)        x = sRel[sm][c];
        else if (c < CIN) x = ftb[(size_t)sIdx[sm] * CFEAT + (c - 3)];
        else              x = 0.f;
        float h2 = __fadd_rn(acc[r], b2c);
        float v = fmaxf(__fmul_rn(h2, x), 0.f);
        if (mt == 0)      sm0 = fmaxf(sm0, v);
        else if (mt < 3)  sm1 = fmaxf(sm1, v);
        else              sm2 = fmaxf(sm2, v);
      }
    }
    // combine the 4 quads (same channel, different samples): 2 shfls per segment
    sm0 = fmaxf(sm0, __shfl_xor(sm0, 16)); sm0 = fmaxf(sm0, __shfl_xor(sm0, 32));
    sm1 = fmaxf(sm1, __shfl_xor(sm1, 16)); sm1 = fmaxf(sm1, __shfl_xor(sm1, 32));
    sm2 = fmaxf(sm2, __shfl_xor(sm2, 16)); sm2 = fmaxf(sm2, __shfl_xor(sm2, 32));
    if (quad == 0 && c < CIN) {
      sPool[0][c] = sm0; sPool[1][c] = sm1; sPool[2][c] = sm2;
    }
  }
  __syncthreads();

  // ---- Phase D: out = relu(pooled @ Wcr + bcr) ----
  if (t < CFEAT) {
    float s0 = bcr[t], s1 = s0, s2 = s0;
#pragma unroll 4
    for (int k = 0; k < CIN; ++k) {
      float w = Wcr[k * CFEAT + t];
      s0 = fmaf(sPool[0][k], w, s0);
      s1 = fmaf(sPool[1][k], w, s1);
      s2 = fmaf(sPool[2][k], w, s2);
    }
    float* ob = out_feat + (size_t)b * 384 * NPOINT + j;
    ob[(size_t)(0 * CFEAT + t) * NPOINT] = fmaxf(s0, 0.f);
    ob[(size_t)(1 * CFEAT + t) * NPOINT] = fmaxf(s1, 0.f);
    ob[(size_t)(2 * CFEAT + t) * NPOINT] = fmaxf(s2, 0.f);
  }
}

extern "C" void kernel_launch(void* const* d_in, const int* in_sizes, int n_in,
                              void* d_out, int out_size, void* d_ws, size_t ws_size,
                              hipStream_t stream) {
  const float* xyz  = (const float*)d_in[0];
  const float* feat = (const float*)d_in[1];
  const float* W1   = (const float*)d_in[2];
  const float* b1   = (const float*)d_in[3];
  const float* W2   = (const float*)d_in[4];
  const float* b2   = (const float*)d_in[5];
  const float* Wcr  = (const float*)d_in[6];
  const float* bcr  = (const float*)d_in[7];
  float* out_xyz  = (float*)d_out;                          // (B, 512, 3)
  float* out_feat = out_xyz + (size_t)BATCH * NPOINT * 3;   // (B, 384, 512)
  float* featT    = (float*)d_ws;                           // (B, N, C) 16 MB

  fps_transpose_kernel<<<BATCH + BATCH * 256, 256, 0, stream>>>(xyz, feat, featT, out_xyz);
  center_kernel<<<dim3(NPOINT, BATCH), 256, 0, stream>>>(
      xyz, featT, W1, b1, W2, b2, Wcr, bcr, (const float*)d_out, out_feat);
}